// Round 3
// baseline (5995.019 us; speedup 1.0000x reference)
//
#include <hip/hip_runtime.h>
#include <cstdint>
#include <cstddef>

#define B_   64
#define S_   49
#define T_   32
#define D_   512
#define V_   32000
#define G3   1536
#define NBLK 256

typedef short s16x8 __attribute__((ext_vector_type(8)));
typedef float v4f   __attribute__((ext_vector_type(4)));

__device__ __forceinline__ float sigm(float x) { return 1.f / (1.f + __expf(-x)); }

__device__ __forceinline__ unsigned short f2bf(float f) {
  unsigned u = __float_as_uint(f);
  return (unsigned short)((u + 0x7FFFu + ((u >> 16) & 1u)) >> 16);
}

// -------- device-scope grid barrier (sense via monotone generation) --------
// cnt at bar[0], gen at bar[16] (separate 64B lines). All NBLK blocks must be
// co-resident: grid=256, 1 block/CU min (LDS 74KB <= 160KB) -> guaranteed.
__device__ __forceinline__ void gridbar(int* bar) {
  __syncthreads();
  if (threadIdx.x == 0) {
    int* cnt = bar;
    int* gen = bar + 16;
    __threadfence();  // release prior global writes (device scope)
    int g = __hip_atomic_load(gen, __ATOMIC_RELAXED, __HIP_MEMORY_SCOPE_AGENT);
    int v = __hip_atomic_fetch_add(cnt, 1, __ATOMIC_ACQ_REL, __HIP_MEMORY_SCOPE_AGENT);
    if (v == NBLK - 1) {
      __hip_atomic_store(cnt, 0, __ATOMIC_RELAXED, __HIP_MEMORY_SCOPE_AGENT);
      __hip_atomic_fetch_add(gen, 1, __ATOMIC_RELEASE, __HIP_MEMORY_SCOPE_AGENT);
    } else {
      while (__hip_atomic_load(gen, __ATOMIC_ACQUIRE, __HIP_MEMORY_SCOPE_AGENT) == g)
        __builtin_amdgcn_s_sleep(2);
    }
    __threadfence();  // acquire: invalidate stale cached lines
  }
  __syncthreads();
}

// ---------------- fp32 -> bf16 conversion ----------------
__global__ __launch_bounds__(256) void k_cvt(const float* __restrict__ in,
                                             unsigned short* __restrict__ out) {
  int i = (blockIdx.x * 256 + threadIdx.x) * 8;
  float4 a = *(const float4*)(in + i);
  float4 b = *(const float4*)(in + i + 4);
  s16x8 o;
  o[0] = (short)f2bf(a.x); o[1] = (short)f2bf(a.y);
  o[2] = (short)f2bf(a.z); o[3] = (short)f2bf(a.w);
  o[4] = (short)f2bf(b.x); o[5] = (short)f2bf(b.y);
  o[6] = (short)f2bf(b.z); o[7] = (short)f2bf(b.w);
  *(s16x8*)(out + i) = o;
}

// ---------------- embedding gather + active mask ----------------
__global__ __launch_bounds__(128) void k_embed(const float* __restrict__ emb,
    const int* __restrict__ seq, const int* __restrict__ length,
    float* __restrict__ x_embed, float* __restrict__ actmask) {
  int m = blockIdx.x;
  int t = m >> 6, b = m & 63;
  int idx = seq[b * T_ + t];
  const float4* src = (const float4*)(emb + (size_t)idx * D_);
  float4* dst = (float4*)(x_embed + (size_t)m * D_);
  dst[threadIdx.x] = src[threadIdx.x];
  if (threadIdx.x == 0) actmask[b * T_ + t] = (t < length[b]) ? 1.f : 0.f;
}

// ---------------- feats mean + scope init ----------------
__global__ __launch_bounds__(256) void k_hmean(const float* __restrict__ feats,
    float* __restrict__ hmean, float* __restrict__ scope) {
  int b = blockIdx.x, tid = threadIdx.x;
  for (int e = tid; e < D_; e += 256) {
    float s = 0.f;
    for (int si = 0; si < S_; ++si) s += feats[((size_t)b * S_ + si) * D_ + e];
    hmean[b * D_ + e] = s * (1.f / 49.f);
  }
  if (tid < S_) scope[b * S_ + tid] = 1.f;
}

// ---------------- generic fp32 GEMM: C[M,N] = X[M,K] @ W[N,ldw].T + bias ----------------
__global__ __launch_bounds__(256) void k_gemm_f32(
    float* __restrict__ C, const float* __restrict__ X, const float* __restrict__ W,
    const float* __restrict__ bias, int N, int K, int ldw) {
  __shared__ __align__(16) float XsT[32][68];
  __shared__ __align__(16) float WsT[32][68];
  const int nbase = blockIdx.x * 64, mbase = blockIdx.y * 64;
  const int tid = threadIdx.x;
  const int lr = tid >> 2;
  const int lk = (tid & 3) * 8;
  const int ty = tid >> 4, tx = tid & 15;
  float acc[4][4] = {};
  for (int k0 = 0; k0 < K; k0 += 32) {
    {
      const float* xs = X + (size_t)(mbase + lr) * K + k0 + lk;
      const float* wsrc = W + (size_t)(nbase + lr) * ldw + k0 + lk;
      float4 x0 = *(const float4*)xs, x1 = *(const float4*)(xs + 4);
      float4 w0 = *(const float4*)wsrc, w1 = *(const float4*)(wsrc + 4);
      XsT[lk + 0][lr] = x0.x; XsT[lk + 1][lr] = x0.y; XsT[lk + 2][lr] = x0.z; XsT[lk + 3][lr] = x0.w;
      XsT[lk + 4][lr] = x1.x; XsT[lk + 5][lr] = x1.y; XsT[lk + 6][lr] = x1.z; XsT[lk + 7][lr] = x1.w;
      WsT[lk + 0][lr] = w0.x; WsT[lk + 1][lr] = w0.y; WsT[lk + 2][lr] = w0.z; WsT[lk + 3][lr] = w0.w;
      WsT[lk + 4][lr] = w1.x; WsT[lk + 5][lr] = w1.y; WsT[lk + 6][lr] = w1.z; WsT[lk + 7][lr] = w1.w;
    }
    __syncthreads();
    #pragma unroll
    for (int kk = 0; kk < 32; ++kk) {
      float4 a4 = *(const float4*)&XsT[kk][ty * 4];
      float4 w4 = *(const float4*)&WsT[kk][tx * 4];
      float av[4] = {a4.x, a4.y, a4.z, a4.w};
      float wv[4] = {w4.x, w4.y, w4.z, w4.w};
      #pragma unroll
      for (int i = 0; i < 4; ++i)
        #pragma unroll
        for (int j = 0; j < 4; ++j)
          acc[i][j] = fmaf(av[i], wv[j], acc[i][j]);
    }
    __syncthreads();
  }
  #pragma unroll
  for (int i = 0; i < 4; ++i) {
    int m = mbase + ty * 4 + i;
    int n = nbase + tx * 4;
    float4 o;
    o.x = acc[i][0] + bias[n + 0];
    o.y = acc[i][1] + bias[n + 1];
    o.z = acc[i][2] + bias[n + 2];
    o.w = acc[i][3] + bias[n + 3];
    *(float4*)&C[(size_t)m * N + n] = o;
  }
}

// ---------------- persistent recurrence kernel ----------------
// 256 blocks (1/CU), 3 grid barriers per step, 32 steps.
// Block k: bs = k&3 (batch slice of 16), g = k>>2 (0..63).
//   P1: rows j1=16g..16g+15 of [W_da(0:512)|W_beta(512:1024)] x 16 batches.
//   P3: j3=8g..8g+7: 3 GRU gate rows each (W_hh half before bar2, W_ih_awe
//       half after), then pointwise h update.
//   P2 (blocks 0..63): attention/softmax/scope/awe/gate for batch b=k.
// Weight slices are block-static -> stay hot in each XCD's L2 across steps.
__global__ __launch_bounds__(256, 1) void k_recur(
    const float* __restrict__ feats, const float* __restrict__ att1,
    const float* __restrict__ gi_embed,
    const float* __restrict__ W_da, const float* __restrict__ b_da,
    const float* __restrict__ W_beta, const float* __restrict__ b_beta,
    const float* __restrict__ W_hh, const float* __restrict__ b_hh,
    const float* __restrict__ W_ih, const float* __restrict__ W_fa,
    const float* __restrict__ b_fa, const int* __restrict__ length,
    float* __restrict__ h, float* __restrict__ scope,
    float* __restrict__ Yp, float* __restrict__ xg,
    float* __restrict__ alphas, unsigned short* __restrict__ Hbuf,
    int* __restrict__ bar) {
  __shared__ __align__(16) float hs[16][516];
  __shared__ __align__(16) float xgs[16][516];
  __shared__ float ph[384];
  __shared__ float px[384];
  __shared__ float att2_s[512];
  __shared__ float gate_s[512];
  __shared__ float att_s[64];
  __shared__ float alpha_s[64];

  const int k = blockIdx.x, tid = threadIdx.x;
  const int bs = k & 3, b0 = bs * 16, g = k >> 2;
  const int j1 = g * 16;     // P1 row base (0..1023)
  const int j3 = g * 8;      // P3 j base (0..511)
  const int lenP2 = (k < 64) ? length[k] : 0;
  const int lenC = length[b0 + (tid & 15)];
  const float bfa0 = b_fa[0];

  for (int t = 0; t < T_; ++t) {
    // ---- stage h slice into LDS ----
    {
      int row = tid >> 4, c0 = (tid & 15) * 4;
      #pragma unroll
      for (int i = 0; i < 8; ++i) {
        int col = c0 + i * 64;
        *(float4*)&hs[row][col] = *(const float4*)&h[(b0 + row) * D_ + col];
      }
    }
    __syncthreads();
    // ---- P1: Yp[b][j] = h[b] . {W_da|W_beta}[j] + bias ----
    {
      int r = tid >> 4, bl = tid & 15;
      int j = j1 + r;
      const float* wrow = (j < 512) ? &W_da[(size_t)j * D_]
                                    : &W_beta[(size_t)(j - 512) * D_];
      float acc = 0.f;
      #pragma unroll 4
      for (int kk = 0; kk < D_; kk += 4) {
        float4 w = *(const float4*)&wrow[kk];
        float4 x = *(const float4*)&hs[bl][kk];
        acc = fmaf(x.x, w.x, fmaf(x.y, w.y, fmaf(x.z, w.z, fmaf(x.w, w.w, acc))));
      }
      acc += (j < 512) ? b_da[j] : b_beta[j - 512];
      Yp[(size_t)(b0 + bl) * 1024 + j] = acc;
    }
    // ---- P3 h-half: ph[gg*128 + jj*16 + bl] = h[b] . W_hh[gg*512+j] + b_hh ----
    for (int tau = tid; tau < 384; tau += 256) {
      int gg = tau >> 7, jj = (tau >> 4) & 7, bl = tau & 15;
      int j = gg * 512 + j3 + jj;
      const float* wrow = &W_hh[(size_t)j * D_];
      float acc = 0.f;
      #pragma unroll 4
      for (int kk = 0; kk < D_; kk += 4) {
        float4 w = *(const float4*)&wrow[kk];
        float4 x = *(const float4*)&hs[bl][kk];
        acc = fmaf(x.x, w.x, fmaf(x.y, w.y, fmaf(x.z, w.z, fmaf(x.w, w.w, acc))));
      }
      ph[tau] = acc + b_hh[j];
    }
    gridbar(bar);   // ---- bar1: Yp complete ----
    // ---- P2 (blocks 0..63): attention for batch b=k ----
    if (k < 64) {
      int b = k;
      bool act = t < lenP2;
      for (int a = tid; a < 512; a += 256) {
        att2_s[a] = Yp[(size_t)b * 1024 + a];
        gate_s[a] = sigm(Yp[(size_t)b * 1024 + 512 + a]);
      }
      __syncthreads();
      int lane = tid & 63, wv = tid >> 6;
      for (int s = wv; s < S_; s += 4) {
        const float* arow = att1 + ((size_t)b * S_ + s) * D_;
        int a0 = lane * 8;
        float p = 0.f;
        #pragma unroll
        for (int jx = 0; jx < 8; ++jx) {
          float v = arow[a0 + jx] + att2_s[a0 + jx];
          v = v > 0.f ? v : 0.f;
          p = fmaf(v, W_fa[a0 + jx], p);
        }
        #pragma unroll
        for (int off = 32; off > 0; off >>= 1) p += __shfl_xor(p, off, 64);
        if (lane == 0) att_s[s] = p + bfa0;
      }
      __syncthreads();
      if (tid < 64) {
        float x = (tid < S_) ? att_s[tid] : -1e30f;
        float m = x;
        #pragma unroll
        for (int off = 32; off > 0; off >>= 1) m = fmaxf(m, __shfl_xor(m, off, 64));
        float e = (tid < S_) ? __expf(x - m) : 0.f;
        float su = e;
        #pragma unroll
        for (int off = 32; off > 0; off >>= 1) su += __shfl_xor(su, off, 64);
        if (tid < S_) alpha_s[tid] = e / su;
      }
      __syncthreads();
      if (tid < S_) {
        float old = scope[b * S_ + tid], al = alpha_s[tid];
        alphas[((size_t)b * T_ + t) * S_ + tid] = act ? old * al : 0.f;
        scope[b * S_ + tid] = act ? old * (1.f - al) : old;
      }
      for (int e = tid; e < D_; e += 256) {
        float aw = 0.f;
        #pragma unroll 7
        for (int s = 0; s < S_; ++s)
          aw = fmaf(alpha_s[s], feats[((size_t)b * S_ + s) * D_ + e], aw);
        xg[b * D_ + e] = gate_s[e] * aw;
      }
    }
    gridbar(bar);   // ---- bar2: xg complete ----
    // ---- stage xg slice ----
    {
      int row = tid >> 4, c0 = (tid & 15) * 4;
      #pragma unroll
      for (int i = 0; i < 8; ++i) {
        int col = c0 + i * 64;
        *(float4*)&xgs[row][col] = *(const float4*)&xg[(b0 + row) * D_ + col];
      }
    }
    __syncthreads();
    // ---- P3 xg-half: px = xg[b] . W_ih[gg*512+j][512:1024] ----
    for (int tau = tid; tau < 384; tau += 256) {
      int gg = tau >> 7, jj = (tau >> 4) & 7, bl = tau & 15;
      int j = gg * 512 + j3 + jj;
      const float* wrow = &W_ih[(size_t)j * 1024 + 512];
      float acc = 0.f;
      #pragma unroll 4
      for (int kk = 0; kk < D_; kk += 4) {
        float4 w = *(const float4*)&wrow[kk];
        float4 x = *(const float4*)&xgs[bl][kk];
        acc = fmaf(x.x, w.x, fmaf(x.y, w.y, fmaf(x.z, w.z, fmaf(x.w, w.w, acc))));
      }
      px[tau] = acc;
    }
    __syncthreads();
    // ---- combine + GRU pointwise + h update (threads 0..127) ----
    if (tid < 128) {
      int jj = tid >> 4, bl = tid & 15;
      int j = j3 + jj, b = b0 + bl;
      const float* gm = &gi_embed[((size_t)t * 64 + b) * G3];
      float r = sigm(px[tid] + ph[tid] + gm[j]);
      float z = sigm(px[128 + tid] + ph[128 + tid] + gm[512 + j]);
      float n = tanhf(px[256 + tid] + gm[1024 + j] + r * ph[256 + tid]);
      float hold = hs[bl][j];
      float hn = (1.f - z) * n + z * hold;
      bool act = t < lenC;
      h[b * D_ + j] = act ? hn : hold;
      Hbuf[((size_t)b * T_ + t) * D_ + j] = f2bf(hn);
    }
    gridbar(bar);   // ---- bar3: h complete ----
  }
}

// ---------------- Phase C: out = actmask * (Hbuf @ Wout.T + b_out) ----------------
__global__ __launch_bounds__(256) void k_outgemm(
    const unsigned short* __restrict__ Hb, const unsigned short* __restrict__ Wb,
    const float* __restrict__ b_out, const float* __restrict__ actmask,
    float* __restrict__ out) {
  __shared__ __align__(16) unsigned short As[128 * 32];
  __shared__ __align__(16) unsigned short Bs[128 * 32];
  const int bid = blockIdx.x;
  const int swz = (bid & 7) * 500 + (bid >> 3);
  const int mb = (swz & 15) * 128;
  const int nb = (swz >> 4) * 128;
  const int tid = threadIdx.x;
  const int l = tid & 63, w = tid >> 6;
  const int wr = w >> 1, wc = w & 1;
  const int lm = l & 15;
  const int kc = l >> 4;
  const int rchunk = (kc ^ ((lm >> 1) & 3)) * 8;
  v4f acc[4][4];
  #pragma unroll
  for (int mi = 0; mi < 4; ++mi)
    #pragma unroll
    for (int ni = 0; ni < 4; ++ni)
      acc[mi][ni] = (v4f){0.f, 0.f, 0.f, 0.f};

  for (int k0 = 0; k0 < 512; k0 += 32) {
    #pragma unroll
    for (int i = 0; i < 2; ++i) {
      int ch = i * 256 + tid;
      int row = ch >> 2, c4 = ch & 3;
      int sc = (c4 ^ ((row >> 1) & 3)) * 8;
      *(int4*)&As[row * 32 + sc] =
          *(const int4*)&Hb[(size_t)(mb + row) * 512 + k0 + c4 * 8];
      *(int4*)&Bs[row * 32 + sc] =
          *(const int4*)&Wb[(size_t)(nb + row) * 512 + k0 + c4 * 8];
    }
    __syncthreads();
    s16x8 af[4], bf[4];
    #pragma unroll
    for (int mi = 0; mi < 4; ++mi)
      af[mi] = *(const s16x8*)&As[(wr * 64 + mi * 16 + lm) * 32 + rchunk];
    #pragma unroll
    for (int ni = 0; ni < 4; ++ni)
      bf[ni] = *(const s16x8*)&Bs[(wc * 64 + ni * 16 + lm) * 32 + rchunk];
    #pragma unroll
    for (int mi = 0; mi < 4; ++mi)
      #pragma unroll
      for (int ni = 0; ni < 4; ++ni)
        acc[mi][ni] = __builtin_amdgcn_mfma_f32_16x16x32_bf16(af[mi], bf[ni], acc[mi][ni], 0, 0, 0);
    __syncthreads();
  }
  #pragma unroll
  for (int ni = 0; ni < 4; ++ni) {
    int n = nb + wc * 64 + ni * 16 + lm;
    float bo = b_out[n];
    #pragma unroll
    for (int mi = 0; mi < 4; ++mi) {
      int m0 = mb + wr * 64 + mi * 16 + (l >> 4) * 4;
      #pragma unroll
      for (int r = 0; r < 4; ++r) {
        int m = m0 + r;
        out[(size_t)m * V_ + n] = actmask[m] * (acc[mi][ni][r] + bo);
      }
    }
  }
}

extern "C" void kernel_launch(void* const* d_in, const int* in_sizes, int n_in,
                              void* d_out, int out_size, void* d_ws, size_t ws_size,
                              hipStream_t stream) {
  const float* feats  = (const float*)d_in[0];
  const int*   seq    = (const int*)d_in[1];
  const int*   length = (const int*)d_in[2];
  const float* emb    = (const float*)d_in[3];
  const float* W_ih   = (const float*)d_in[4];
  const float* b_ih   = (const float*)d_in[5];
  const float* W_hh   = (const float*)d_in[6];
  const float* b_hh   = (const float*)d_in[7];
  const float* W_out  = (const float*)d_in[8];
  const float* b_out  = (const float*)d_in[9];
  const float* W_init = (const float*)d_in[10];
  const float* b_init = (const float*)d_in[11];
  const float* W_beta = (const float*)d_in[12];
  const float* b_beta = (const float*)d_in[13];
  const float* W_ea   = (const float*)d_in[14];
  const float* b_ea   = (const float*)d_in[15];
  const float* W_da   = (const float*)d_in[16];
  const float* b_da   = (const float*)d_in[17];
  const float* W_fa   = (const float*)d_in[18];
  const float* b_fa   = (const float*)d_in[19];

  float* out    = (float*)d_out;
  float* alphas = out + (size_t)B_ * T_ * V_;

  float* ws = (float*)d_ws;
  float* h        = ws; ws += B_ * D_;
  float* scope    = ws; ws += B_ * S_;
  float* hmean    = ws; ws += B_ * D_;
  float* xg       = ws; ws += B_ * D_;
  float* actmask  = ws; ws += B_ * T_;
  float* Yp       = ws; ws += B_ * 1024;
  float* x_embed  = ws; ws += (size_t)B_ * T_ * D_;
  float* gi_embed = ws; ws += (size_t)B_ * T_ * G3;
  float* att1     = ws; ws += (size_t)B_ * S_ * D_;
  unsigned short* Hbuf  = (unsigned short*)ws;
  unsigned short* Woutb = Hbuf + (size_t)B_ * T_ * D_;
  int* bar = (int*)(Woutb + (size_t)V_ * D_);

  // barrier state must be zero at kernel start each launch
  hipMemsetAsync(bar, 0, 256, stream);

  // ---- Phase A: precompute (parallel) ----
  k_cvt<<<(V_ * D_) / 2048, 256, 0, stream>>>(W_out, Woutb);
  k_embed<<<B_ * T_, 128, 0, stream>>>(emb, seq, length, x_embed, actmask);
  k_hmean<<<B_, 256, 0, stream>>>(feats, hmean, scope);
  k_gemm_f32<<<dim3(8, 1), 256, 0, stream>>>(h, hmean, W_init, b_init, 512, 512, 512);
  k_gemm_f32<<<dim3(8, 49), 256, 0, stream>>>(att1, feats, W_ea, b_ea, 512, 512, 512);
  k_gemm_f32<<<dim3(24, 32), 256, 0, stream>>>(gi_embed, x_embed, W_ih, b_ih, 1536, 512, 1024);

  // ---- Phase B: persistent recurrence (one launch, 96 grid barriers) ----
  k_recur<<<NBLK, 256, 0, stream>>>(feats, att1, gi_embed,
      W_da, b_da, W_beta, b_beta, W_hh, b_hh, W_ih, W_fa, b_fa, length,
      h, scope, Yp, xg, alphas, Hbuf, bar);

  // ---- Phase C: deferred output projection ----
  k_outgemm<<<4000, 256, 0, stream>>>(Hbuf, Woutb, b_out, actmask, out);
}

// Round 4
// 2565.348 us; speedup vs baseline: 2.3369x; 2.3369x over previous
//
#include <hip/hip_runtime.h>
#include <cstdint>
#include <cstddef>

#define B_   64
#define S_   49
#define T_   32
#define D_   512
#define V_   32000
#define G3   1536
#define NBLK 256

typedef short s16x8 __attribute__((ext_vector_type(8)));
typedef float v4f   __attribute__((ext_vector_type(4)));
typedef _Float16 f16;
typedef _Float16 f16x8 __attribute__((ext_vector_type(8)));

__device__ __forceinline__ float sigm(float x) { return 1.f / (1.f + __expf(-x)); }

// ---------------- fp32 -> f16 conversion (8 elems/thread) ----------------
__global__ __launch_bounds__(256) void k_cvt16(const float* __restrict__ in,
                                               f16* __restrict__ out) {
  int i = (blockIdx.x * 256 + threadIdx.x) * 8;
  float4 a = *(const float4*)(in + i);
  float4 b = *(const float4*)(in + i + 4);
  f16x8 o;
  o[0] = (f16)a.x; o[1] = (f16)a.y; o[2] = (f16)a.z; o[3] = (f16)a.w;
  o[4] = (f16)b.x; o[5] = (f16)b.y; o[6] = (f16)b.z; o[7] = (f16)b.w;
  *(f16x8*)(out + i) = o;
}

// ---------------- embedding gather + active mask ----------------
__global__ __launch_bounds__(128) void k_embed(const float* __restrict__ emb,
    const int* __restrict__ seq, const int* __restrict__ length,
    float* __restrict__ x_embed, float* __restrict__ actmask) {
  int m = blockIdx.x;
  int t = m >> 6, b = m & 63;
  int idx = seq[b * T_ + t];
  const float4* src = (const float4*)(emb + (size_t)idx * D_);
  float4* dst = (float4*)(x_embed + (size_t)m * D_);
  dst[threadIdx.x] = src[threadIdx.x];
  if (threadIdx.x == 0) actmask[b * T_ + t] = (t < length[b]) ? 1.f : 0.f;
}

// ---------------- feats mean + scope init ----------------
__global__ __launch_bounds__(256) void k_hmean(const float* __restrict__ feats,
    float* __restrict__ hmean, float* __restrict__ scope) {
  int b = blockIdx.x, tid = threadIdx.x;
  for (int e = tid; e < D_; e += 256) {
    float s = 0.f;
    for (int si = 0; si < S_; ++si) s += feats[((size_t)b * S_ + si) * D_ + e];
    hmean[b * D_ + e] = s * (1.f / 49.f);
  }
  if (tid < S_) scope[b * S_ + tid] = 1.f;
}

// ---------------- generic fp32 GEMM: C[M,N] = X[M,K] @ W[N,ldw].T + bias ----------------
__global__ __launch_bounds__(256) void k_gemm_f32(
    float* __restrict__ C, const float* __restrict__ X, const float* __restrict__ W,
    const float* __restrict__ bias, int N, int K, int ldw) {
  __shared__ __align__(16) float XsT[32][68];
  __shared__ __align__(16) float WsT[32][68];
  const int nbase = blockIdx.x * 64, mbase = blockIdx.y * 64;
  const int tid = threadIdx.x;
  const int lr = tid >> 2;
  const int lk = (tid & 3) * 8;
  const int ty = tid >> 4, tx = tid & 15;
  float acc[4][4] = {};
  for (int k0 = 0; k0 < K; k0 += 32) {
    {
      const float* xs = X + (size_t)(mbase + lr) * K + k0 + lk;
      const float* wsrc = W + (size_t)(nbase + lr) * ldw + k0 + lk;
      float4 x0 = *(const float4*)xs, x1 = *(const float4*)(xs + 4);
      float4 w0 = *(const float4*)wsrc, w1 = *(const float4*)(wsrc + 4);
      XsT[lk + 0][lr] = x0.x; XsT[lk + 1][lr] = x0.y; XsT[lk + 2][lr] = x0.z; XsT[lk + 3][lr] = x0.w;
      XsT[lk + 4][lr] = x1.x; XsT[lk + 5][lr] = x1.y; XsT[lk + 6][lr] = x1.z; XsT[lk + 7][lr] = x1.w;
      WsT[lk + 0][lr] = w0.x; WsT[lk + 1][lr] = w0.y; WsT[lk + 2][lr] = w0.z; WsT[lk + 3][lr] = w0.w;
      WsT[lk + 4][lr] = w1.x; WsT[lk + 5][lr] = w1.y; WsT[lk + 6][lr] = w1.z; WsT[lk + 7][lr] = w1.w;
    }
    __syncthreads();
    #pragma unroll
    for (int kk = 0; kk < 32; ++kk) {
      float4 a4 = *(const float4*)&XsT[kk][ty * 4];
      float4 w4 = *(const float4*)&WsT[kk][tx * 4];
      float av[4] = {a4.x, a4.y, a4.z, a4.w};
      float wv[4] = {w4.x, w4.y, w4.z, w4.w};
      #pragma unroll
      for (int i = 0; i < 4; ++i)
        #pragma unroll
        for (int j = 0; j < 4; ++j)
          acc[i][j] = fmaf(av[i], wv[j], acc[i][j]);
    }
    __syncthreads();
  }
  #pragma unroll
  for (int i = 0; i < 4; ++i) {
    int m = mbase + ty * 4 + i;
    int n = nbase + tx * 4;
    float4 o;
    o.x = acc[i][0] + bias[n + 0];
    o.y = acc[i][1] + bias[n + 1];
    o.z = acc[i][2] + bias[n + 2];
    o.w = acc[i][3] + bias[n + 3];
    *(float4*)&C[(size_t)m * N + n] = o;
  }
}

// ---------------- pack kernels (phase A) ----------------
// Wpack1[K][slot 0..9][512]: slots = {Wda 2K, Wda 2K+1, Wbe 2K, Wbe 2K+1,
//   Whh r j0, r j1, z j0, z j1, n j0, n j1}
__global__ __launch_bounds__(256) void k_packW(
    const float* __restrict__ Wda, const float* __restrict__ Wbe,
    const float* __restrict__ Whh, const float* __restrict__ Wih,
    f16* __restrict__ Wp1, f16* __restrict__ Wp2) {
  int K = blockIdx.x, tid = threadIdx.x;
  for (int idx = tid; idx < 5120; idx += 256) {
    int s = idx >> 9, e = idx & 511;
    float v;
    if (s < 2)      v = Wda[(size_t)(2 * K + s) * D_ + e];
    else if (s < 4) v = Wbe[(size_t)(2 * K + s - 2) * D_ + e];
    else { int g = (s - 4) >> 1, jj = (s - 4) & 1;
           v = Whh[(size_t)(g * 512 + 2 * K + jj) * D_ + e]; }
    Wp1[(size_t)K * 5120 + idx] = (f16)v;
  }
  for (int idx = tid; idx < 3072; idx += 256) {
    int s = idx >> 9, e = idx & 511;
    int g = s >> 1, jj = s & 1;
    float v = Wih[(size_t)(g * 512 + 2 * K + jj) * 1024 + 512 + e];
    Wp2[(size_t)K * 3072 + idx] = (f16)v;
  }
}

// feats->f16, att1->f16, h0->f16
__global__ __launch_bounds__(256) void k_packF(
    const float* __restrict__ feats, const float* __restrict__ att1,
    const float* __restrict__ h0,
    f16* __restrict__ feats16, f16* __restrict__ att116, f16* __restrict__ h16) {
  const int NF = B_ * S_ * D_;
  for (size_t i = blockIdx.x * 256 + threadIdx.x; i < 2 * NF + B_ * D_;
       i += (size_t)gridDim.x * 256) {
    if (i < NF)           feats16[i] = (f16)feats[i];
    else if (i < 2 * NF)  att116[i - NF] = (f16)att1[i - NF];
    else                  h16[i - 2 * NF] = (f16)h0[i - 2 * NF];
  }
}

// gi_pack[t][K][b][8]: slots 0..5 = gi_embed r j0, r j1, z j0, z j1, n j0, n j1
__global__ __launch_bounds__(256) void k_packG(
    const float* __restrict__ gi_embed, float* __restrict__ gi_pack) {
  for (size_t i = blockIdx.x * 256 + threadIdx.x; i < (size_t)T_ * 256 * 64 * 8;
       i += (size_t)gridDim.x * 256) {
    int slot = i & 7;
    int b = (i >> 3) & 63;
    int K = (i >> 9) & 255;
    int t = i >> 17;
    float v = 0.f;
    if (slot < 6) {
      int g = slot >> 1, jj = slot & 1;
      v = gi_embed[((size_t)t * 64 + b) * G3 + g * 512 + 2 * K + jj];
    }
    gi_pack[i] = v;
  }
}

// ---------------- persistent recurrence: LDS-resident weights ----------------
// 256 blocks x 256 threads (4 waves). Block K owns hidden j-pair {2K, 2K+1}.
// LDS-resident: W1 (10 cols matvec1), W2 (6 cols matvec2) -- fences never
// touch LDS, so the per-step L2 invalidation (R2's 752MB refetch bug) now
// costs only KBs of cross-block state.
// Per step: [64,512]@[512,16] MFMA x2 (f16), attention by blocks 0..63,
// pointwise local to the j-pair. Sync: 3 monotone device-scope counters.
__global__ __launch_bounds__(256, 1) void k_recur(
    const f16* __restrict__ Wp1, const f16* __restrict__ Wp2,
    const f16* __restrict__ att116, const f16* __restrict__ feats16,
    const float* __restrict__ gi_pack,
    const float* __restrict__ b_da, const float* __restrict__ b_beta,
    const float* __restrict__ b_hh,
    const float* __restrict__ W_fa, const float* __restrict__ b_fa,
    const int* __restrict__ length,
    f16* __restrict__ h16, f16* __restrict__ xg16,
    float* __restrict__ att2g, float* __restrict__ scope,
    float* __restrict__ alphas, f16* __restrict__ Hbuf,
    int* __restrict__ ctr) {
  __shared__ __align__(16) uint4 hs[4096];      // 64KB: h or xg staged, swizzled
  __shared__ __align__(16) uint4 W1[1024];      // 16KB (slots 10..15 unused)
  __shared__ __align__(16) uint4 W2[1024];      // 16KB (slots 6..15 unused)
  __shared__ float gh_lds[64][6];
  __shared__ float gix_lds[64][6];
  __shared__ float att2_s[512];
  __shared__ float gate_s[512];
  __shared__ float att_s[64];
  __shared__ float alpha_s[64];

  const int K = blockIdx.x, tid = threadIdx.x;
  const int w = tid >> 6, l = tid & 63;
  const int lm = l & 15, c4 = l >> 4;
  int* c1 = ctr; int* c2 = ctr + 16; int* c3 = ctr + 32;

  // stage LDS-resident weight slices (once)
  {
    const uint4* s1 = (const uint4*)(Wp1 + (size_t)K * 5120);
    const uint4* s2 = (const uint4*)(Wp2 + (size_t)K * 3072);
    #pragma unroll
    for (int i = 0; i < 3; ++i) {
      int g = i * 256 + tid;
      if (g < 640) { int s = g >> 6, c = g & 63; W1[s * 64 + (c ^ (s & 7))] = s1[g]; }
    }
    #pragma unroll
    for (int i = 0; i < 2; ++i) {
      int g = i * 256 + tid;
      if (g < 384) { int s = g >> 6, c = g & 63; W2[s * 64 + (c ^ (s & 7))] = s2[g]; }
    }
  }
  // per-thread constants
  const int lenP2 = (K < 64) ? length[K] : 0;
  const float bfa0 = b_fa[0];
  int   lb = 0; float bhr = 0.f, bhz = 0.f, bhn = 0.f;
  if (tid < 128) {
    int b = tid >> 1, jj = tid & 1;
    lb = length[b];
    bhr = b_hh[0 * 512 + 2 * K + jj];
    bhz = b_hh[1 * 512 + 2 * K + jj];
    bhn = b_hh[2 * 512 + 2 * K + jj];
  }
  __syncthreads();

  for (int t = 0; t < T_; ++t) {
    // ---- wait h(t) ready; stage into LDS (swizzled) ----
    if (tid == 0) {
      while (__hip_atomic_load(c3, __ATOMIC_RELAXED, __HIP_MEMORY_SCOPE_AGENT) < NBLK * t)
        __builtin_amdgcn_s_sleep(2);
      __threadfence();
    }
    __syncthreads();
    {
      const uint4* src = (const uint4*)h16;
      #pragma unroll
      for (int i = 0; i < 16; ++i) {
        int g = i * 256 + tid;
        int b = g >> 6, c = g & 63;
        hs[b * 64 + (c ^ (b & 7))] = src[g];
      }
    }
    __syncthreads();
    // ---- matvec1: [64,512]@[512,16] -> att2(4) | gh(6) ----
    {
      v4f acc = {0.f, 0.f, 0.f, 0.f};
      int bb = w * 16 + lm;
      #pragma unroll
      for (int kt = 0; kt < 16; ++kt) {
        int ca = kt * 4 + c4;
        f16x8 a = __builtin_bit_cast(f16x8, hs[bb * 64 + (ca ^ (bb & 7))]);
        f16x8 bf = __builtin_bit_cast(f16x8, W1[lm * 64 + (ca ^ (lm & 7))]);
        acc = __builtin_amdgcn_mfma_f32_16x16x32_f16(a, bf, acc, 0, 0, 0);
      }
      #pragma unroll
      for (int r = 0; r < 4; ++r) {
        int b = w * 16 + c4 * 4 + r;
        if (lm < 4)       att2g[b * 1024 + K * 4 + lm] = acc[r];
        else if (lm < 10) gh_lds[b][lm - 4] = acc[r];
      }
    }
    // ---- bump ctr1 (att2g visible) ----
    __syncthreads();
    if (tid == 0) {
      __threadfence();
      __hip_atomic_fetch_add(c1, 1, __ATOMIC_RELEASE, __HIP_MEMORY_SCOPE_AGENT);
    }
    // ---- P2: attention (blocks 0..63, batch b=K) ----
    if (K < 64) {
      if (tid == 0) {
        while (__hip_atomic_load(c1, __ATOMIC_RELAXED, __HIP_MEMORY_SCOPE_AGENT) < NBLK * (t + 1))
          __builtin_amdgcn_s_sleep(2);
        __threadfence();
      }
      __syncthreads();
      int b = K;
      bool act = t < lenP2;
      for (int a = tid; a < 512; a += 256) {
        float v1 = att2g[b * 1024 + 4 * (a >> 1) + (a & 1)];
        float v2 = att2g[b * 1024 + 4 * (a >> 1) + 2 + (a & 1)];
        att2_s[a] = v1 + b_da[a];
        gate_s[a] = sigm(v2 + b_beta[a]);
      }
      __syncthreads();
      int lane = tid & 63, wv = tid >> 6;
      for (int s = wv; s < S_; s += 4) {
        const f16x8* arow = (const f16x8*)(att116 + ((size_t)b * S_ + s) * D_);
        int a0 = lane * 8;
        f16x8 av = arow[lane];
        float p = 0.f;
        #pragma unroll
        for (int jx = 0; jx < 8; ++jx) {
          float v = (float)av[jx] + att2_s[a0 + jx];
          v = v > 0.f ? v : 0.f;
          p = fmaf(v, W_fa[a0 + jx], p);
        }
        #pragma unroll
        for (int off = 32; off > 0; off >>= 1) p += __shfl_xor(p, off, 64);
        if (lane == 0) att_s[s] = p + bfa0;
      }
      __syncthreads();
      if (tid < 64) {
        float x = (tid < S_) ? att_s[tid] : -1e30f;
        float m = x;
        #pragma unroll
        for (int off = 32; off > 0; off >>= 1) m = fmaxf(m, __shfl_xor(m, off, 64));
        float e = (tid < S_) ? __expf(x - m) : 0.f;
        float su = e;
        #pragma unroll
        for (int off = 32; off > 0; off >>= 1) su += __shfl_xor(su, off, 64);
        if (tid < S_) alpha_s[tid] = e / su;
      }
      __syncthreads();
      if (tid < S_) {
        float old = scope[b * S_ + tid], al = alpha_s[tid];
        alphas[((size_t)b * T_ + t) * S_ + tid] = act ? old * al : 0.f;
        scope[b * S_ + tid] = act ? old * (1.f - al) : old;
      }
      for (int e = tid; e < D_; e += 256) {
        float aw = 0.f;
        #pragma unroll 7
        for (int s = 0; s < S_; ++s)
          aw = fmaf(alpha_s[s], (float)feats16[((size_t)b * S_ + s) * D_ + e], aw);
        xg16[b * D_ + e] = (f16)(gate_s[e] * aw);
      }
      __syncthreads();
      if (tid == 0) {
        __threadfence();
        __hip_atomic_fetch_add(c2, 1, __ATOMIC_RELEASE, __HIP_MEMORY_SCOPE_AGENT);
      }
    }
    // ---- wait xg ready; stage into LDS ----
    if (tid == 0) {
      while (__hip_atomic_load(c2, __ATOMIC_RELAXED, __HIP_MEMORY_SCOPE_AGENT) < 64 * (t + 1))
        __builtin_amdgcn_s_sleep(2);
      __threadfence();
    }
    __syncthreads();
    {
      const uint4* src = (const uint4*)xg16;
      #pragma unroll
      for (int i = 0; i < 16; ++i) {
        int g = i * 256 + tid;
        int b = g >> 6, c = g & 63;
        hs[b * 64 + (c ^ (b & 7))] = src[g];
      }
    }
    __syncthreads();
    // ---- matvec2: [64,512]@[512,16] -> gix(6) ----
    {
      v4f acc = {0.f, 0.f, 0.f, 0.f};
      int bb = w * 16 + lm;
      #pragma unroll
      for (int kt = 0; kt < 16; ++kt) {
        int ca = kt * 4 + c4;
        f16x8 a = __builtin_bit_cast(f16x8, hs[bb * 64 + (ca ^ (bb & 7))]);
        f16x8 bf = __builtin_bit_cast(f16x8, W2[lm * 64 + (ca ^ (lm & 7))]);
        acc = __builtin_amdgcn_mfma_f32_16x16x32_f16(a, bf, acc, 0, 0, 0);
      }
      #pragma unroll
      for (int r = 0; r < 4; ++r) {
        int b = w * 16 + c4 * 4 + r;
        if (lm < 6) gix_lds[b][lm] = acc[r];
      }
    }
    __syncthreads();
    // ---- pointwise GRU for own j-pair ----
    if (tid < 128) {
      int b = tid >> 1, jj = tid & 1;
      const float* gp = gi_pack + (((size_t)t * 256 + K) * 64 + b) * 8;
      float r = sigm(gix_lds[b][0 + jj] + gp[0 + jj] + gh_lds[b][0 + jj] + bhr);
      float z = sigm(gix_lds[b][2 + jj] + gp[2 + jj] + gh_lds[b][2 + jj] + bhz);
      float n = tanhf(gix_lds[b][4 + jj] + gp[4 + jj] + r * (gh_lds[b][4 + jj] + bhn));
      int j = 2 * K + jj;
      float hold = (float)h16[b * D_ + j];
      float hn = (1.f - z) * n + z * hold;
      bool act = t < lb;
      h16[b * D_ + j] = (f16)(act ? hn : hold);
      Hbuf[((size_t)b * T_ + t) * D_ + j] = (f16)hn;
    }
    __syncthreads();
    if (tid == 0) {
      __threadfence();
      __hip_atomic_fetch_add(c3, 1, __ATOMIC_RELEASE, __HIP_MEMORY_SCOPE_AGENT);
    }
  }
}

// ---------------- Phase C: out = actmask * (Hbuf @ Wout.T + b_out), f16 MFMA ----------------
__global__ __launch_bounds__(256) void k_outgemm(
    const f16* __restrict__ Hb, const f16* __restrict__ Wb,
    const float* __restrict__ b_out, const float* __restrict__ actmask,
    float* __restrict__ out) {
  __shared__ __align__(16) f16 As[128 * 32];
  __shared__ __align__(16) f16 Bs[128 * 32];
  const int bid = blockIdx.x;
  const int swz = (bid & 7) * 500 + (bid >> 3);
  const int mb = (swz & 15) * 128;
  const int nb = (swz >> 4) * 128;
  const int tid = threadIdx.x;
  const int l = tid & 63, w = tid >> 6;
  const int wr = w >> 1, wc = w & 1;
  const int lm = l & 15;
  const int kc = l >> 4;
  const int rchunk = (kc ^ ((lm >> 1) & 3)) * 8;
  v4f acc[4][4];
  #pragma unroll
  for (int mi = 0; mi < 4; ++mi)
    #pragma unroll
    for (int ni = 0; ni < 4; ++ni)
      acc[mi][ni] = (v4f){0.f, 0.f, 0.f, 0.f};

  for (int k0 = 0; k0 < 512; k0 += 32) {
    #pragma unroll
    for (int i = 0; i < 2; ++i) {
      int ch = i * 256 + tid;
      int row = ch >> 2, cq = ch & 3;
      int sc = (cq ^ ((row >> 1) & 3)) * 8;
      *(int4*)&As[row * 32 + sc] =
          *(const int4*)&Hb[(size_t)(mb + row) * 512 + k0 + cq * 8];
      *(int4*)&Bs[row * 32 + sc] =
          *(const int4*)&Wb[(size_t)(nb + row) * 512 + k0 + cq * 8];
    }
    __syncthreads();
    f16x8 af[4], bf[4];
    #pragma unroll
    for (int mi = 0; mi < 4; ++mi)
      af[mi] = *(const f16x8*)&As[(wr * 64 + mi * 16 + lm) * 32 + rchunk];
    #pragma unroll
    for (int ni = 0; ni < 4; ++ni)
      bf[ni] = *(const f16x8*)&Bs[(wc * 64 + ni * 16 + lm) * 32 + rchunk];
    #pragma unroll
    for (int mi = 0; mi < 4; ++mi)
      #pragma unroll
      for (int ni = 0; ni < 4; ++ni)
        acc[mi][ni] = __builtin_amdgcn_mfma_f32_16x16x32_f16(af[mi], bf[ni], acc[mi][ni], 0, 0, 0);
    __syncthreads();
  }
  #pragma unroll
  for (int ni = 0; ni < 4; ++ni) {
    int n = nb + wc * 64 + ni * 16 + lm;
    float bo = b_out[n];
    #pragma unroll
    for (int mi = 0; mi < 4; ++mi) {
      int m0 = mb + wr * 64 + mi * 16 + (l >> 4) * 4;
      #pragma unroll
      for (int r = 0; r < 4; ++r) {
        int m = m0 + r;
        out[(size_t)m * V_ + n] = actmask[m] * (acc[mi][ni][r] + bo);
      }
    }
  }
}

extern "C" void kernel_launch(void* const* d_in, const int* in_sizes, int n_in,
                              void* d_out, int out_size, void* d_ws, size_t ws_size,
                              hipStream_t stream) {
  const float* feats  = (const float*)d_in[0];
  const int*   seq    = (const int*)d_in[1];
  const int*   length = (const int*)d_in[2];
  const float* emb    = (const float*)d_in[3];
  const float* W_ih   = (const float*)d_in[4];
  const float* b_ih   = (const float*)d_in[5];
  const float* W_hh   = (const float*)d_in[6];
  const float* b_hh   = (const float*)d_in[7];
  const float* W_out  = (const float*)d_in[8];
  const float* b_out  = (const float*)d_in[9];
  const float* W_init = (const float*)d_in[10];
  const float* b_init = (const float*)d_in[11];
  const float* W_beta = (const float*)d_in[12];
  const float* b_beta = (const float*)d_in[13];
  const float* W_ea   = (const float*)d_in[14];
  const float* b_ea   = (const float*)d_in[15];
  const float* W_da   = (const float*)d_in[16];
  const float* b_da   = (const float*)d_in[17];
  const float* W_fa   = (const float*)d_in[18];
  const float* b_fa   = (const float*)d_in[19];

  float* out    = (float*)d_out;
  float* alphas = out + (size_t)B_ * T_ * V_;

  // ---- workspace layout ----
  float* ws = (float*)d_ws;
  int*   ctr      = (int*)ws;        ws += 64;           // 3 counters, 64B apart
  float* h0       = ws;              ws += B_ * D_;
  float* hmean    = ws;              ws += B_ * D_;
  float* scope    = ws;              ws += 4096;
  float* actmask  = ws;              ws += B_ * T_;
  float* att2g    = ws;              ws += B_ * 1024;
  float* x_embed  = ws;              ws += (size_t)B_ * T_ * D_;
  float* gi_embed = ws;              ws += (size_t)B_ * T_ * G3;
  float* gi_pack  = ws;              ws += (size_t)T_ * 256 * 64 * 8;
  float* att1     = ws;              ws += (size_t)B_ * S_ * D_;
  f16* fp = (f16*)ws;
  f16* Woutb   = fp;  fp += (size_t)V_ * D_;
  f16* Hbuf    = fp;  fp += (size_t)B_ * T_ * D_;
  f16* Wp1     = fp;  fp += (size_t)256 * 5120;
  f16* Wp2     = fp;  fp += (size_t)256 * 3072;
  f16* feats16 = fp;  fp += (size_t)B_ * S_ * D_;
  f16* att116  = fp;  fp += (size_t)B_ * S_ * D_;
  f16* h16     = fp;  fp += B_ * D_;
  f16* xg16    = fp;  fp += B_ * D_;

  hipMemsetAsync(ctr, 0, 256, stream);

  // ---- Phase A ----
  k_cvt16<<<(V_ * D_) / 2048, 256, 0, stream>>>(W_out, Woutb);
  k_embed<<<B_ * T_, 128, 0, stream>>>(emb, seq, length, x_embed, actmask);
  k_hmean<<<B_, 256, 0, stream>>>(feats, hmean, scope);
  k_gemm_f32<<<dim3(8, 1), 256, 0, stream>>>(h0, hmean, W_init, b_init, 512, 512, 512);
  k_gemm_f32<<<dim3(8, 49), 256, 0, stream>>>(att1, feats, W_ea, b_ea, 512, 512, 512);
  k_gemm_f32<<<dim3(24, 32), 256, 0, stream>>>(gi_embed, x_embed, W_ih, b_ih, 1536, 512, 1024);
  k_packW<<<256, 256, 0, stream>>>(W_da, W_beta, W_hh, W_ih, Wp1, Wp2);
  k_packF<<<2048, 256, 0, stream>>>(feats, att1, h0, feats16, att116, h16);
  k_packG<<<2048, 256, 0, stream>>>(gi_embed, gi_pack);

  // ---- Phase B: persistent recurrence, LDS-resident weights ----
  k_recur<<<NBLK, 256, 0, stream>>>(Wp1, Wp2, att116, feats16, gi_pack,
      b_da, b_beta, b_hh, W_fa, b_fa, length,
      h16, xg16, att2g, scope, alphas, Hbuf, ctr);

  // ---- Phase C ----
  k_outgemm<<<4000, 256, 0, stream>>>(Hbuf, Woutb, b_out, actmask, out);
}